// Round 1
// baseline (812.072 us; speedup 1.0000x reference)
//
#include <hip/hip_runtime.h>
#include <stdint.h>

#define IN_F 1024
#define OUT_F 1024
#define INT_DIM 128
#define M_ROWS 16384  // 8 * 2048

#define BM 128
#define BN 128
#define BK 32

typedef float f32x4 __attribute__((ext_vector_type(4)));
typedef __bf16 bf16x8 __attribute__((ext_vector_type(8)));

// round-to-nearest-even fp32 -> bf16 (finite inputs only)
__device__ __forceinline__ unsigned short f2bf(float f) {
  unsigned int u = __float_as_uint(f);
  u += 0x7fffu + ((u >> 16) & 1u);
  return (unsigned short)(u >> 16);
}

// async global->LDS, 16B per lane (wave-uniform base + lane*16 on HW side;
// our LDS layout is contiguous in lane order so per-lane ptr == base+lane*16)
__device__ __forceinline__ void async_copy16(void* lds_dst, const void* gsrc) {
  __builtin_amdgcn_global_load_lds(
      (const __attribute__((address_space(1))) void*)gsrc,
      (__attribute__((address_space(3))) void*)lds_dst, 16, 0, 0);
}

// ---------------------------------------------------------------------------
// Kernel 1: W_bf16[o*IN_F + i] = sum_d coef[d] * P_w[d][o*IN_F + i]
// 512 MB stream, memory-bound. One float4 column chunk per thread.
// ---------------------------------------------------------------------------
__global__ void expand_w_kernel(const float* __restrict__ coef,
                                const float* __restrict__ Pw,
                                unsigned short* __restrict__ W) {
  __shared__ float c[INT_DIM];
  if (threadIdx.x < INT_DIM) c[threadIdx.x] = coef[threadIdx.x];
  __syncthreads();
  const int j4 = blockIdx.x * 256 + threadIdx.x;  // 0 .. 262143
  const float4* P4 = (const float4*)Pw;
  float4 acc = make_float4(0.f, 0.f, 0.f, 0.f);
#pragma unroll 8
  for (int d = 0; d < INT_DIM; ++d) {
    float4 p = P4[(size_t)d * (OUT_F * IN_F / 4) + j4];
    float cd = c[d];
    acc.x += cd * p.x;
    acc.y += cd * p.y;
    acc.z += cd * p.z;
    acc.w += cd * p.w;
  }
  union { unsigned short us[4]; uint2 u; } o;
  o.us[0] = f2bf(acc.x);
  o.us[1] = f2bf(acc.y);
  o.us[2] = f2bf(acc.z);
  o.us[3] = f2bf(acc.w);
  ((uint2*)W)[j4] = o.u;
}

// ---------------------------------------------------------------------------
// Kernel 2: bias[o] = sum_d bias_coef[d] * P_b[d][o]   (fp32, tiny)
// ---------------------------------------------------------------------------
__global__ void expand_b_kernel(const float* __restrict__ coef,
                                const float* __restrict__ Pb,
                                float* __restrict__ bias) {
  const int o = blockIdx.x * 256 + threadIdx.x;
  float acc = 0.f;
#pragma unroll 8
  for (int d = 0; d < INT_DIM; ++d) acc += coef[d] * Pb[d * OUT_F + o];
  bias[o] = acc;
}

// ---------------------------------------------------------------------------
// Kernel 3: x fp32 -> bf16 (96 MB traffic, memory-bound)
// ---------------------------------------------------------------------------
__global__ void cvt_x_kernel(const float4* __restrict__ x,
                             uint2* __restrict__ xb) {
  const int i = blockIdx.x * 256 + threadIdx.x;  // exact cover, no tail
  float4 v = x[i];
  union { unsigned short us[4]; uint2 u; } o;
  o.us[0] = f2bf(v.x);
  o.us[1] = f2bf(v.y);
  o.us[2] = f2bf(v.z);
  o.us[3] = f2bf(v.w);
  xb[i] = o.u;
}

// ---------------------------------------------------------------------------
// Kernel 4: m97-style bf16 GEMM, C[m][n] = sum_k A[m][k]*B[n][k] + bias[n]
// A: [M][K] bf16 (x), B: [N][K] bf16 (W, already B^T layout), C fp32.
// 128x128 tile, BK=32, 4 waves (2x2), 4x4 16x16x32 MFMA frags per wave.
// ---------------------------------------------------------------------------
__global__ __launch_bounds__(256) void gemm_bt_kernel(
    const unsigned short* __restrict__ A,
    const unsigned short* __restrict__ B,
    const float* __restrict__ bias,
    float* __restrict__ C) {
  constexpr int K = IN_F;
  constexpr int N = OUT_F;
  __shared__ unsigned short sA[BM * BK];  // 8 KB, row-major [128][32], no pad
  __shared__ unsigned short sB[BN * BK];  // 8 KB

  const int tid = threadIdx.x;
  const int bm = blockIdx.y * BM;
  const int bn = blockIdx.x * BN;
  const int lane = tid & 63;
  const int wave = tid >> 6;
  const int wm = (wave >> 1) * 64;
  const int wn = (wave & 1) * 64;
  const int lm = lane & 15;
  const int quad = lane >> 4;

  // staging: tile = 512 16B chunks; each of 256 threads stages 2 per operand
  const int q0 = tid;
  const int q1 = tid + 256;
  const int r0 = q0 >> 2, kc0 = (q0 & 3) * 8;
  const int r1 = q1 >> 2, kc1 = (q1 & 3) * 8;

  f32x4 acc[4][4];
  const f32x4 zero = {0.f, 0.f, 0.f, 0.f};
#pragma unroll
  for (int i = 0; i < 4; ++i)
#pragma unroll
    for (int j = 0; j < 4; ++j) acc[i][j] = zero;

  for (int k0 = 0; k0 < K; k0 += BK) {
    async_copy16(&sA[q0 * 8], &A[(size_t)(bm + r0) * K + k0 + kc0]);
    async_copy16(&sA[q1 * 8], &A[(size_t)(bm + r1) * K + k0 + kc1]);
    async_copy16(&sB[q0 * 8], &B[(size_t)(bn + r0) * K + k0 + kc0]);
    async_copy16(&sB[q1 * 8], &B[(size_t)(bn + r1) * K + k0 + kc1]);
    __syncthreads();  // drains vmcnt -> staging complete

    bf16x8 af[4], bf[4];
#pragma unroll
    for (int f = 0; f < 4; ++f)
      af[f] = *(const bf16x8*)&sA[(wm + f * 16 + lm) * BK + quad * 8];
#pragma unroll
    for (int f = 0; f < 4; ++f)
      bf[f] = *(const bf16x8*)&sB[(wn + f * 16 + lm) * BK + quad * 8];

#pragma unroll
    for (int fm = 0; fm < 4; ++fm)
#pragma unroll
      for (int fn = 0; fn < 4; ++fn)
        acc[fm][fn] = __builtin_amdgcn_mfma_f32_16x16x32_bf16(
            af[fm], bf[fn], acc[fm][fn], 0, 0, 0);
    __syncthreads();  // protect LDS from next-iter overwrite
  }

  // epilogue: D layout col=lane&15, row=quad*4+reg (verified m89/m91)
  float bv[4];
#pragma unroll
  for (int fn = 0; fn < 4; ++fn) bv[fn] = bias[bn + wn + fn * 16 + lm];
#pragma unroll
  for (int fm = 0; fm < 4; ++fm) {
#pragma unroll
    for (int r = 0; r < 4; ++r) {
      const int row = bm + wm + fm * 16 + quad * 4 + r;
      float* crow = C + (size_t)row * N + bn + wn + lm;
#pragma unroll
      for (int fn = 0; fn < 4; ++fn) crow[fn * 16] = acc[fm][fn][r] + bv[fn];
    }
  }
}

extern "C" void kernel_launch(void* const* d_in, const int* in_sizes, int n_in,
                              void* d_out, int out_size, void* d_ws,
                              size_t ws_size, hipStream_t stream) {
  const float* x = (const float*)d_in[0];    // [8,2048,1024] fp32
  const float* wc = (const float*)d_in[1];   // [128]
  const float* bc = (const float*)d_in[2];   // [128]
  const float* Pw = (const float*)d_in[3];   // [128, 1048576]
  const float* Pb = (const float*)d_in[4];   // [128, 1024]
  float* out = (float*)d_out;                // [8,2048,1024] fp32

  // workspace layout (needs 36 MB):
  //   [0, 2MB)      W bf16  [1024][1024]
  //   [2MB, 2MB+4K) bias fp32 [1024]
  //   [4MB, 36MB)   x bf16  [16384][1024]
  unsigned short* W = (unsigned short*)d_ws;
  float* bias = (float*)((char*)d_ws + (2u << 20));
  unsigned short* xb = (unsigned short*)((char*)d_ws + (4u << 20));

  expand_w_kernel<<<OUT_F * IN_F / 4 / 256, 256, 0, stream>>>(wc, Pw, W);
  expand_b_kernel<<<OUT_F / 256, 256, 0, stream>>>(bc, Pb, bias);
  cvt_x_kernel<<<(M_ROWS * IN_F / 4) / 256, 256, 0, stream>>>(
      (const float4*)x, (uint2*)xb);

  dim3 grid(OUT_F / BN, M_ROWS / BM);  // (8, 128)
  gemm_bt_kernel<<<grid, 256, 0, stream>>>(xb, W, bias, out);
}